// Round 1
// 462.376 us; speedup vs baseline: 1.0018x; 1.0018x over previous
//
#include <hip/hip_runtime.h>

#define E_EXT 128
#define EH 64            // E_EXT / 2 : elements per block half
#define S_SEG 64
#define P_PATH 256
#define SE 8192          // S_SEG * E_EXT

// ws layout:
//   [0, 260)          : int seg_start[S_SEG+1]
//   [1024, 1024+4096) : int4 meta[P_PATH]  {i1*64, i2*64, coeff_bits, i3}
// NOTE: i1*64 is simultaneously (a) the float2 offset of segment i1 in a full
// row and (b) the float offset of segment i1 in a half-row [seg][64] layout.
// The E-split main kernel uses interpretation (b); build_paths is unchanged.

__global__ __launch_bounds__(P_PATH) void build_paths_kernel(
    const float* __restrict__ coeff,
    const int* __restrict__ pidx,
    int* __restrict__ seg_start,
    int4* __restrict__ meta)
{
    __shared__ int i3s[P_PATH];
    __shared__ int cnt[S_SEG];
    __shared__ int base[S_SEG + 1];
    const int t = threadIdx.x;
    const int i1 = pidx[3 * t + 0];
    const int i2 = pidx[3 * t + 1];
    const int i3 = pidx[3 * t + 2];
    i3s[t] = i3;
    __syncthreads();
    // deterministic rank of path t within its segment
    int pos = 0;
    for (int q = 0; q < t; ++q) pos += (i3s[q] == i3) ? 1 : 0;
    if (t < S_SEG) {
        int c = 0;
        for (int q = 0; q < P_PATH; ++q) c += (i3s[q] == t) ? 1 : 0;
        cnt[t] = c;
    }
    __syncthreads();
    if (t == 0) {
        int run = 0;
        for (int s = 0; s < S_SEG; ++s) { base[s] = run; run += cnt[s]; }
        base[S_SEG] = run;
    }
    __syncthreads();
    if (t <= S_SEG) seg_start[t] = base[t];
    meta[base[i3] + pos] = make_int4(i1 * EH, i2 * EH,
                                     __float_as_int(coeff[t]), i3);
}

// One block per (batch b, E-half h). LDS = 16K(x) + 16K(y) + 4K(meta) + 260B
// ≈ 36.3 KB -> 4 blocks/CU (vs 68.3 KB -> 2 blocks/CU before). 32 waves/CU.
__global__ __launch_bounds__(512, 8) void tp_main_kernel(
    const float* __restrict__ x_table,
    const float* __restrict__ y,
    const int* __restrict__ x_idx,
    const int* __restrict__ seg_start,
    const int4* __restrict__ meta,
    float* __restrict__ out)
{
    __shared__ float xs[S_SEG * EH];   // 16 KB : [seg][64] half-row of x
    __shared__ float ys[S_SEG * EH];   // 16 KB : [seg][64] half-row of y
    __shared__ int4 smeta[P_PATH];     // 4 KB
    __shared__ int sstart[S_SEG + 1];

    const int bb = blockIdx.x;
    const int b  = bb >> 1;
    const int h  = bb & 1;             // which half of E this block owns
    const int t  = threadIdx.x;

    // Stage the h-half of the gathered x row and of the y row.
    // Half-row = 64 runs of 256 B (stride 512 B). 16-lane groups read
    // contiguous 256 B -> fully consumed cache lines, coalesced.
    const float4* __restrict__ xsrc =
        (const float4*)(x_table + (size_t)x_idx[b] * SE) + h * (EH / 4);
    const float4* __restrict__ ysrc =
        (const float4*)(y + (size_t)b * SE) + h * (EH / 4);
    float4* xd = (float4*)xs;
    float4* yd = (float4*)ys;
#pragma unroll
    for (int i = 0; i < 2; ++i) {      // 1024 float4 per array / 512 threads
        const int j = t + i * 512;     // LDS float4 slot
        const int g = ((j >> 4) << 5) + (j & 15);  // seg*32 + off in full row
        xd[j] = xsrc[g];
        yd[j] = ysrc[g];
    }
    if (t < P_PATH) smeta[t] = meta[t];
    if (t <= S_SEG) sstart[t] = seg_start[t];
    __syncthreads();

    const int w = t >> 6;   // wave 0..7 -> owns segments [8w, 8w+8)
    const int l = t & 63;   // lane      -> owns element e = h*64 + l
    float* __restrict__ orow = out + (size_t)b * SE + h * EH;

    for (int si = 0; si < 8; ++si) {
        const int s3 = w * 8 + si;
        const int js = sstart[s3];       // LDS broadcast
        const int je = sstart[s3 + 1];
        float a = 0.f;
        int4 r;
        if (js < je) r = smeta[js];      // prime the pipeline
        for (int j = js; j < je; ++j) {
            const int4 cur = r;
            if (j + 1 < je) r = smeta[j + 1];  // prefetch next meta (broadcast)
            const float c = __int_as_float(cur.z);
            a = fmaf(c * xs[cur.x + l], ys[cur.y + l], a);
        }
        orow[(size_t)s3 * E_EXT + l] = a;   // 256 B contiguous per wave
    }
}

extern "C" void kernel_launch(void* const* d_in, const int* in_sizes, int n_in,
                              void* d_out, int out_size, void* d_ws, size_t ws_size,
                              hipStream_t stream) {
    const float* x_table   = (const float*)d_in[0];
    const float* y         = (const float*)d_in[1];
    const float* path_coef = (const float*)d_in[2];
    const int*   x_idx     = (const int*)d_in[3];
    const int*   path_idx  = (const int*)d_in[4];
    float* out = (float*)d_out;

    int* seg_start = (int*)d_ws;
    int4* meta = (int4*)((char*)d_ws + 1024);

    const int B = in_sizes[3];  // 4096 (x_idx count)

    build_paths_kernel<<<1, P_PATH, 0, stream>>>(path_coef, path_idx, seg_start, meta);
    tp_main_kernel<<<2 * B, 512, 0, stream>>>(x_table, y, x_idx, seg_start, meta, out);
}